// Round 1
// baseline (477.833 us; speedup 1.0000x reference)
//
#include <hip/hip_runtime.h>
#include <math.h>

#define N_DIM 64
#define C_DIM 512
#define K_DIM 64
#define P_DIM 900
#define EPSN  1e-12f

// ---------------------------------------------------------------------------
// Kernel 1: per-pixel logits (1x1 conv) + softmax over K, fused with the
// L2-norm reduction over C (invn folded in AFTER the GEMM since it's linear).
// Writes a2[n,k,p] = softmax_k * invn(p)   (ready for the agg GEMM)
// and asum_part[n,k,ptile] = sum_{p in tile} softmax_k  (raw a, no invn).
// ---------------------------------------------------------------------------
__global__ __launch_bounds__(256) void netvlad_assign(
    const float* __restrict__ x, const float* __restrict__ w,
    float* __restrict__ a2, float* __restrict__ asum_part)
{
  const int n   = blockIdx.y;
  const int pt  = blockIdx.x;              // 0..3, 256 pixels each (900 total)
  const int tid = threadIdx.x;
  const int p   = pt * 256 + tid;
  const bool valid = p < P_DIM;
  const int pc  = valid ? p : (P_DIM - 1); // clamp for safe reads

  const float* xp = x + (size_t)n * C_DIM * P_DIM + pc;

  float logit[K_DIM];
#pragma unroll
  for (int k = 0; k < K_DIM; ++k) logit[k] = 0.f;
  float sumsq = 0.f;

  __shared__ float wlds[64][68];   // wlds[c_local][k], padded (write 8-way ok)
  __shared__ float red[4][K_DIM];

  for (int c0 = 0; c0 < C_DIM; c0 += 64) {
    __syncthreads();
    // stage 64x64 chunk of W, transposed: coalesced global read
#pragma unroll
    for (int i = 0; i < 16; ++i) {
      int flat = i * 256 + tid;
      int k  = flat >> 6;
      int cc = flat & 63;
      wlds[cc][k] = w[k * C_DIM + c0 + cc];
    }
    __syncthreads();
#pragma unroll 4
    for (int cc = 0; cc < 64; ++cc) {
      float xv = xp[(size_t)(c0 + cc) * P_DIM];   // coalesced across lanes
      sumsq += xv * xv;
#pragma unroll
      for (int k4 = 0; k4 < 16; ++k4) {
        float4 wv = *(const float4*)&wlds[cc][k4 * 4];  // broadcast read
        logit[k4 * 4 + 0] += wv.x * xv;
        logit[k4 * 4 + 1] += wv.y * xv;
        logit[k4 * 4 + 2] += wv.z * xv;
        logit[k4 * 4 + 3] += wv.w * xv;
      }
    }
  }

  const float invn = 1.0f / fmaxf(sqrtf(sumsq), EPSN);

  // thread-local softmax over the 64 logits
  float m = -INFINITY;
#pragma unroll
  for (int k = 0; k < K_DIM; ++k) { logit[k] *= invn; m = fmaxf(m, logit[k]); }
  float s = 0.f;
#pragma unroll
  for (int k = 0; k < K_DIM; ++k) { logit[k] = __expf(logit[k] - m); s += logit[k]; }
  const float rs = 1.0f / s;
  const float vscale = valid ? rs : 0.0f;   // invalid pixels contribute a=0

  const int wave = tid >> 6;
  const int lane = tid & 63;
  float* a2p = a2 + (size_t)n * K_DIM * P_DIM;

#pragma unroll
  for (int k = 0; k < K_DIM; ++k) {
    float a = logit[k] * vscale;                       // softmax value (0 if invalid)
    if (valid) a2p[(size_t)k * P_DIM + p] = a * invn;  // fold invn for agg GEMM
    float av = a;
#pragma unroll
    for (int off = 32; off; off >>= 1) av += __shfl_xor(av, off);
    if (lane == 0) red[wave][k] = av;
  }
  __syncthreads();
  if (tid < K_DIM) {
    float t = red[0][tid] + red[1][tid] + red[2][tid] + red[3][tid];
    asum_part[((size_t)n * K_DIM + tid) * 4 + pt] = t;
  }
}

// ---------------------------------------------------------------------------
// Kernel 2: agg[n,k,c] = sum_p a2[n,k,p] * x[n,c,p]; vlad = agg - asum*cent.
// Tiled NT-GEMM: per block (n, 64-wide c tile), full K=64, Pt=64 LDS tiles.
// Thread owns a 4k x 4c accumulator block.
// ---------------------------------------------------------------------------
#define PT 64

__global__ __launch_bounds__(256) void netvlad_agg(
    const float* __restrict__ x, const float* __restrict__ cent,
    const float* __restrict__ a2, const float* __restrict__ asum_part,
    float* __restrict__ out)
{
  const int n   = blockIdx.y;
  const int c0  = blockIdx.x * 64;
  const int tid = threadIdx.x;
  const int kg  = tid >> 4;      // 0..15 -> k0 = kg*4
  const int cg  = tid & 15;      // c_local = cg*4
  const int k0  = kg * 4;

  __shared__ float a_lds[64][66];   // [k][p], pad 66 -> conflict-free 4-way reads
  __shared__ float x_lds[PT][68];   // [p][c], pad 68 -> float4 reads clean
  __shared__ float asum_l[64];

  if (tid < 64) {
    const float* pp = asum_part + ((size_t)n * K_DIM + tid) * 4;
    asum_l[tid] = pp[0] + pp[1] + pp[2] + pp[3];
  }

  float acc[4][4];
#pragma unroll
  for (int i = 0; i < 4; ++i)
#pragma unroll
    for (int j = 0; j < 4; ++j) acc[i][j] = 0.f;

  const float* xb = x  + (size_t)n * C_DIM * P_DIM;
  const float* ab = a2 + (size_t)n * K_DIM * P_DIM;

  for (int p0 = 0; p0 < P_DIM; p0 += PT) {   // 15 tiles (last is 4 pixels)
    __syncthreads();
#pragma unroll
    for (int i = 0; i < 16; ++i) {
      int flat = i * 256 + tid;
      int r   = flat >> 6;        // k for a, c_local for x
      int pp2 = flat & 63;
      int p   = p0 + pp2;
      bool ok = p < P_DIM;
      a_lds[r][pp2] = ok ? ab[(size_t)r * P_DIM + p] : 0.f;
      x_lds[pp2][r] = ok ? xb[(size_t)(c0 + r) * P_DIM + p] : 0.f;
    }
    __syncthreads();
#pragma unroll 8
    for (int pp2 = 0; pp2 < PT; ++pp2) {
      float4 xv = *(const float4*)&x_lds[pp2][cg * 4];
      float a0v = a_lds[k0 + 0][pp2];
      float a1v = a_lds[k0 + 1][pp2];
      float a2v = a_lds[k0 + 2][pp2];
      float a3v = a_lds[k0 + 3][pp2];
      acc[0][0] += a0v * xv.x; acc[0][1] += a0v * xv.y; acc[0][2] += a0v * xv.z; acc[0][3] += a0v * xv.w;
      acc[1][0] += a1v * xv.x; acc[1][1] += a1v * xv.y; acc[1][2] += a1v * xv.z; acc[1][3] += a1v * xv.w;
      acc[2][0] += a2v * xv.x; acc[2][1] += a2v * xv.y; acc[2][2] += a2v * xv.z; acc[2][3] += a2v * xv.w;
      acc[3][0] += a3v * xv.x; acc[3][1] += a3v * xv.y; acc[3][2] += a3v * xv.z; acc[3][3] += a3v * xv.w;
    }
  }

  // epilogue: vlad = agg - asum * centroid
#pragma unroll
  for (int i = 0; i < 4; ++i) {
    int k = k0 + i;
    float as = asum_l[k];
    float4 cv = *(const float4*)&cent[(size_t)k * C_DIM + c0 + cg * 4];
    float4 o;
    o.x = acc[i][0] - as * cv.x;
    o.y = acc[i][1] - as * cv.y;
    o.z = acc[i][2] - as * cv.z;
    o.w = acc[i][3] - as * cv.w;
    *(float4*)&out[((size_t)n * K_DIM + k) * C_DIM + c0 + cg * 4] = o;
  }
}

extern "C" void kernel_launch(void* const* d_in, const int* in_sizes, int n_in,
                              void* d_out, int out_size, void* d_ws, size_t ws_size,
                              hipStream_t stream) {
  const float* x    = (const float*)d_in[0];
  const float* w    = (const float*)d_in[1];
  const float* cent = (const float*)d_in[2];
  float* out = (float*)d_out;

  float* a2        = (float*)d_ws;                              // N*K*P floats
  float* asum_part = a2 + (size_t)N_DIM * K_DIM * P_DIM;        // N*K*4 floats

  netvlad_assign<<<dim3(4, N_DIM), 256, 0, stream>>>(x, w, a2, asum_part);
  netvlad_agg<<<dim3(8, N_DIM), 256, 0, stream>>>(x, cent, a2, asum_part, out);
}

// Round 4
// 288.043 us; speedup vs baseline: 1.6589x; 1.6589x over previous
//
#include <hip/hip_runtime.h>
#include <math.h>

#define N_DIM 64
#define C_DIM 512
#define K_DIM 64
#define P_DIM 900
#define EPSN  1e-12f
#define PTILES 15          // ceil(900/64)
#define PHALF  450

#define A2_ELEMS   ((size_t)N_DIM * K_DIM * P_DIM)
#define ASUM_ELEMS ((size_t)N_DIM * K_DIM * PTILES)
#define WT_ELEMS   ((size_t)C_DIM * K_DIM)

// ---------------------------------------------------------------------------
// Kernel T: transpose W [K,C] -> wt [C,K] so assign staging is coalesced AND
// LDS-write conflict-free. 128 KB, runs once, trivial cost.
// ---------------------------------------------------------------------------
__global__ __launch_bounds__(256) void transpose_w(
    const float* __restrict__ w, float* __restrict__ wt)
{
  int idx = blockIdx.x * 256 + threadIdx.x;     // 0..8191
  int k  = idx >> 7;
  int c4 = (idx & 127) * 4;
  float4 v = *(const float4*)&w[k * C_DIM + c4];
  wt[(c4 + 0) * K_DIM + k] = v.x;
  wt[(c4 + 1) * K_DIM + k] = v.y;
  wt[(c4 + 2) * K_DIM + k] = v.z;
  wt[(c4 + 3) * K_DIM + k] = v.w;
}

// ---------------------------------------------------------------------------
// Kernel A: fused invn + logits GEMM (64k x 64p tile) + softmax.
// Grid (15 ptiles, 64 n), 256 threads, thread tile 4k x 4p.
// Writes a2[n,k,p] = softmax * invn(p), asum_part[n,k,ptile] = sum_p softmax.
// ---------------------------------------------------------------------------
__global__ __launch_bounds__(256) void netvlad_assign(
    const float* __restrict__ x, const float* __restrict__ wt,
    float* __restrict__ a2, float* __restrict__ asum_part)
{
  const int n   = blockIdx.y;
  const int pt  = blockIdx.x;
  const int p0  = pt * 64;
  const int tid = threadIdx.x;

  __shared__ float wlds[32][68];     // [c_local][k]
  __shared__ float xlds[32][64];     // [c_local][p]
  __shared__ float lmat[64][68];     // [k][p] logits -> softmax probs
  __shared__ float red[4][64];
  __shared__ float invn_lds[64];

  const int pl_st = tid & 63;        // pixel this thread stages
  const int cgrp  = tid >> 6;        // 0..3
  const int gp    = p0 + pl_st;
  const bool pvalid = gp < P_DIM;

  const int kf4 = (tid >> 4) * 4;    // k fragment base
  const int pf4 = (tid & 15) * 4;    // p fragment base

  const float* xb = x + (size_t)n * C_DIM * P_DIM;

  float acc[4][4] = {{0.f}};
  float ssq = 0.f;

  for (int c0 = 0; c0 < C_DIM; c0 += 32) {
    __syncthreads();
    // stage W chunk (from pre-transposed wt): coalesced read, stride-1 write
#pragma unroll
    for (int i = 0; i < 8; ++i) {
      int flat = i * 256 + tid;
      int cc = flat >> 6;            // 0..31
      int k  = flat & 63;
      wlds[cc][k] = wt[(size_t)(c0 + cc) * K_DIM + k];
    }
    // stage x chunk + fused sumsq: coalesced read, stride-1 write
#pragma unroll
    for (int i = 0; i < 8; ++i) {
      int cc = i * 4 + cgrp;
      float v = pvalid ? xb[(size_t)(c0 + cc) * P_DIM + gp] : 0.f;
      xlds[cc][pl_st] = v;
      ssq += v * v;
    }
    __syncthreads();
#pragma unroll
    for (int cc = 0; cc < 32; ++cc) {
      float4 wv = *(const float4*)&wlds[cc][kf4];
      float4 xv = *(const float4*)&xlds[cc][pf4];
      acc[0][0] += wv.x * xv.x; acc[0][1] += wv.x * xv.y; acc[0][2] += wv.x * xv.z; acc[0][3] += wv.x * xv.w;
      acc[1][0] += wv.y * xv.x; acc[1][1] += wv.y * xv.y; acc[1][2] += wv.y * xv.z; acc[1][3] += wv.y * xv.w;
      acc[2][0] += wv.z * xv.x; acc[2][1] += wv.z * xv.y; acc[2][2] += wv.z * xv.z; acc[2][3] += wv.z * xv.w;
      acc[3][0] += wv.w * xv.x; acc[3][1] += wv.w * xv.y; acc[3][2] += wv.w * xv.z; acc[3][3] += wv.w * xv.w;
    }
  }

  // publish sumsq partials and logits
  red[cgrp][pl_st] = ssq;
#pragma unroll
  for (int ki = 0; ki < 4; ++ki)
    *(float4*)&lmat[kf4 + ki][pf4] =
        make_float4(acc[ki][0], acc[ki][1], acc[ki][2], acc[ki][3]);
  __syncthreads();

  // per-pixel softmax (wave 0, one pixel per lane, column reads conflict-free)
  if (tid < 64) {
    float s4 = red[0][tid] + red[1][tid] + red[2][tid] + red[3][tid];
    float scale = 1.0f / fmaxf(sqrtf(s4), EPSN);
    invn_lds[tid] = scale;
    bool v = (p0 + tid) < P_DIM;
    float m = -INFINITY;
#pragma unroll 8
    for (int k = 0; k < K_DIM; ++k) m = fmaxf(m, lmat[k][tid] * scale);
    float s = 0.f;
#pragma unroll 8
    for (int k = 0; k < K_DIM; ++k) {
      float e = __expf(lmat[k][tid] * scale - m);
      lmat[k][tid] = e;
      s += e;
    }
    float rs = v ? (1.0f / s) : 0.0f;   // invalid pixels -> a = 0
#pragma unroll 8
    for (int k = 0; k < K_DIM; ++k) lmat[k][tid] *= rs;
  }
  __syncthreads();

  // asum partials (raw softmax, summed over this block's pixels)
  if (tid < 64) {
    float s = 0.f;
#pragma unroll 8
    for (int pl = 0; pl < 64; ++pl) s += lmat[tid][pl];
    asum_part[((size_t)n * K_DIM + tid) * PTILES + pt] = s;
  }

  // cooperative a2 = a * invn write (coalesced over p)
  float* a2p = a2 + (size_t)n * K_DIM * P_DIM;
#pragma unroll
  for (int i = 0; i < 16; ++i) {
    int flat = i * 256 + tid;
    int k  = flat >> 6;
    int pl = flat & 63;
    int p  = p0 + pl;
    if (p < P_DIM) a2p[(size_t)k * P_DIM + p] = lmat[k][pl] * invn_lds[pl];
  }
}

// ---------------------------------------------------------------------------
// Kernel B: partial agg over a P half: aggpart[h,n,k,c] = sum_{p in half} a2*x
// Grid (8 ctiles, 2 halves, 64 n), 256 threads, thread tile 4k x 4c.
// ---------------------------------------------------------------------------
__global__ __launch_bounds__(256) void netvlad_agg(
    const float* __restrict__ x, const float* __restrict__ a2,
    float* __restrict__ aggpart)
{
  const int n   = blockIdx.z;
  const int h   = blockIdx.y;
  const int c0  = blockIdx.x * 64;
  const int tid = threadIdx.x;
  const int k0  = (tid >> 4) * 4;
  const int cg4 = (tid & 15) * 4;

  __shared__ float a_lds[64][66];    // [k][p]
  __shared__ float x_lds[64][68];    // [p][c]

  float acc[4][4] = {{0.f}};
  const float* xb = x  + (size_t)n * C_DIM * P_DIM;
  const float* ab = a2 + (size_t)n * K_DIM * P_DIM;
  const int pbase = h * PHALF;
  const int plim  = pbase + PHALF;

  for (int j = 0; j < 8; ++j) {      // 8 x 64 covers 450 (last tile ragged)
    const int p0 = pbase + j * 64;
    __syncthreads();
#pragma unroll
    for (int i = 0; i < 16; ++i) {
      int flat = i * 256 + tid;
      int r  = flat >> 6;
      int pp = flat & 63;
      int p  = p0 + pp;
      bool ok = p < plim;
      a_lds[r][pp] = ok ? ab[(size_t)r * P_DIM + p] : 0.f;
      x_lds[pp][r] = ok ? xb[(size_t)(c0 + r) * P_DIM + p] : 0.f;
    }
    __syncthreads();
#pragma unroll 8
    for (int pp = 0; pp < 64; ++pp) {
      float4 xv = *(const float4*)&x_lds[pp][cg4];
      float a0 = a_lds[k0 + 0][pp];
      float a1 = a_lds[k0 + 1][pp];
      float a2v = a_lds[k0 + 2][pp];
      float a3 = a_lds[k0 + 3][pp];
      acc[0][0] += a0 * xv.x; acc[0][1] += a0 * xv.y; acc[0][2] += a0 * xv.z; acc[0][3] += a0 * xv.w;
      acc[1][0] += a1 * xv.x; acc[1][1] += a1 * xv.y; acc[1][2] += a1 * xv.z; acc[1][3] += a1 * xv.w;
      acc[2][0] += a2v * xv.x; acc[2][1] += a2v * xv.y; acc[2][2] += a2v * xv.z; acc[2][3] += a2v * xv.w;
      acc[3][0] += a3 * xv.x; acc[3][1] += a3 * xv.y; acc[3][2] += a3 * xv.z; acc[3][3] += a3 * xv.w;
    }
  }

#pragma unroll
  for (int ki = 0; ki < 4; ++ki) {
    size_t o = ((((size_t)h * N_DIM + n) * K_DIM) + k0 + ki) * C_DIM + c0 + cg4;
    *(float4*)&aggpart[o] = make_float4(acc[ki][0], acc[ki][1], acc[ki][2], acc[ki][3]);
  }
}

// ---------------------------------------------------------------------------
// Kernel C: out[n,k,c] = aggpart0 + aggpart1 - asum[n,k] * cent[k,c]
// ---------------------------------------------------------------------------
__global__ __launch_bounds__(128) void netvlad_epilogue(
    const float* __restrict__ aggpart, const float* __restrict__ asum_part,
    const float* __restrict__ cent, float* __restrict__ out)
{
  const int bx  = blockIdx.x;        // n*64 + k
  const int k   = bx & 63;
  const int tid = threadIdx.x;
  __shared__ float s_asum;
  if (tid == 0) {
    float s = 0.f;
#pragma unroll
    for (int j = 0; j < PTILES; ++j) s += asum_part[(size_t)bx * PTILES + j];
    s_asum = s;
  }
  __syncthreads();
  const float as = s_asum;
  const int c4 = tid * 4;
  float4 g0 = *(const float4*)&aggpart[(size_t)bx * C_DIM + c4];
  float4 g1 = *(const float4*)&aggpart[((size_t)N_DIM * K_DIM + bx) * C_DIM + c4];
  float4 cv = *(const float4*)&cent[(size_t)k * C_DIM + c4];
  float4 o;
  o.x = g0.x + g1.x - as * cv.x;
  o.y = g0.y + g1.y - as * cv.y;
  o.z = g0.z + g1.z - as * cv.z;
  o.w = g0.w + g1.w - as * cv.w;
  *(float4*)&out[(size_t)bx * C_DIM + c4] = o;
}

extern "C" void kernel_launch(void* const* d_in, const int* in_sizes, int n_in,
                              void* d_out, int out_size, void* d_ws, size_t ws_size,
                              hipStream_t stream) {
  const float* x    = (const float*)d_in[0];
  const float* w    = (const float*)d_in[1];
  const float* cent = (const float*)d_in[2];
  float* out = (float*)d_out;

  float* a2        = (float*)d_ws;
  float* asum_part = a2 + A2_ELEMS;
  float* wt        = asum_part + ASUM_ELEMS;
  float* aggpart   = wt + WT_ELEMS;

  transpose_w     <<<32, 256, 0, stream>>>(w, wt);
  netvlad_assign  <<<dim3(PTILES, N_DIM), 256, 0, stream>>>(x, wt, a2, asum_part);
  netvlad_agg     <<<dim3(8, 2, N_DIM), 256, 0, stream>>>(x, a2, aggpart);
  netvlad_epilogue<<<dim3(N_DIM * K_DIM), 128, 0, stream>>>(aggpart, asum_part, cent, out);
}

// Round 5
// 93.088 us; speedup vs baseline: 5.1331x; 3.0943x over previous
//
#include <hip/hip_runtime.h>
#include <math.h>

#define N_DIM 64
#define C_DIM 512
#define K_DIM 64
#define P_DIM 900
#define P_PAD 928          // 29 * 32 (agg K-steps of 32)
#define PTILES 15          // assign p-blocks of 64
#define XS_STRIDE 1040     // bytes per p-row in assign LDS: 512*2 + 16 pad

typedef __attribute__((ext_vector_type(8))) short short8;   // 8 bf16 = 4 VGPR
typedef __attribute__((ext_vector_type(4))) float f32x4;    // MFMA C/D

#define A2_ELEMS   ((size_t)N_DIM * K_DIM * P_PAD)

// fp32 -> bf16 bits, round-to-nearest-even (inputs finite)
__device__ inline ushort f2bf(float f) {
  uint u = __builtin_bit_cast(uint, f);
  u += 0x7FFFu + ((u >> 16) & 1u);
  return (ushort)(u >> 16);
}

// ---------------------------------------------------------------------------
// Kernel A: logits GEMM via MFMA + fused L2-norm + softmax.
// Block = (p-tile of 64, n). 4 waves; wave w owns k in [16w,16w+16), 4 p-subtiles.
// x staged fp32->bf16 transposed into LDS [p][c]; W fragments preloaded to regs.
// Writes a2[n,k,p] = softmax*invn (bf16, zero-padded to P_PAD),
//        asum_part[n,k,ptile] = sum_p softmax (fp32).
// ---------------------------------------------------------------------------
__global__ __launch_bounds__(256) void netvlad_assign(
    const float* __restrict__ x, const float* __restrict__ w,
    ushort* __restrict__ a2, float* __restrict__ asum_part)
{
  const int n = blockIdx.y, bpt = blockIdx.x, p0 = bpt * 64;
  const int tid = threadIdx.x, wave = tid >> 6, lane = tid & 63;
  const int l15 = lane & 15, lhi = lane >> 4;

  __shared__ char  xs[64 * XS_STRIDE];   // [p][c] bf16, padded rows
  __shared__ float red[4][64];
  __shared__ float invn_s[64];
  __shared__ float wredm[4][4][16];
  __shared__ float wreds[4][4][16];

  // ---- stage x: coalesced fp32 reads over p, bf16 packed b64 writes; fused ssq
  const float* xb = x + (size_t)n * C_DIM * P_DIM;
  const int ps = tid & 63;               // this thread's pixel row in LDS
  const int cq = (tid >> 6) * 4;         // c-quad offset within 16-chunk
  const int gp = p0 + ps;
  const bool pv = gp < P_DIM;
  float ssq = 0.f;
  for (int c0 = 0; c0 < C_DIM; c0 += 16) {
    int c = c0 + cq;
    float v0 = pv ? xb[(size_t)(c + 0) * P_DIM + gp] : 0.f;
    float v1 = pv ? xb[(size_t)(c + 1) * P_DIM + gp] : 0.f;
    float v2 = pv ? xb[(size_t)(c + 2) * P_DIM + gp] : 0.f;
    float v3 = pv ? xb[(size_t)(c + 3) * P_DIM + gp] : 0.f;
    ssq += v0 * v0 + v1 * v1 + v2 * v2 + v3 * v3;
    unsigned long long pk =
        (unsigned long long)f2bf(v0) | ((unsigned long long)f2bf(v1) << 16) |
        ((unsigned long long)f2bf(v2) << 32) | ((unsigned long long)f2bf(v3) << 48);
    *(unsigned long long*)(xs + (size_t)ps * XS_STRIDE + (size_t)c * 2) = pk;
  }
  red[wave][ps] = ssq;

  // ---- W fragment preload (fp32 -> bf16 regs), k-ordering = ks*32 + lhi*8 + j
  short8 wfrag[16];
  const float* wrow = w + (size_t)(wave * 16 + l15) * C_DIM + lhi * 8;
#pragma unroll
  for (int ks = 0; ks < 16; ++ks) {
    float4 f0 = *(const float4*)(wrow + ks * 32);
    float4 f1 = *(const float4*)(wrow + ks * 32 + 4);
    short8 t;
    t[0] = (short)f2bf(f0.x); t[1] = (short)f2bf(f0.y);
    t[2] = (short)f2bf(f0.z); t[3] = (short)f2bf(f0.w);
    t[4] = (short)f2bf(f1.x); t[5] = (short)f2bf(f1.y);
    t[6] = (short)f2bf(f1.z); t[7] = (short)f2bf(f1.w);
    wfrag[ks] = t;
  }
  __syncthreads();   // xs + red ready

  if (tid < 64) {
    float s = red[0][tid] + red[1][tid] + red[2][tid] + red[3][tid];
    invn_s[tid] = ((p0 + tid) < P_DIM) ? (1.0f / fmaxf(sqrtf(s), 1e-12f)) : 0.f;
  }

  // ---- MFMA: C[m=k][n=p]; same k-slot ordering for A and B fragments
  f32x4 acc[4];
#pragma unroll
  for (int pt = 0; pt < 4; ++pt) acc[pt] = (f32x4){0.f, 0.f, 0.f, 0.f};
#pragma unroll
  for (int ks = 0; ks < 16; ++ks) {
#pragma unroll
    for (int pt = 0; pt < 4; ++pt) {
      short8 xfrag = *(const short8*)(xs + (size_t)(pt * 16 + l15) * XS_STRIDE
                                         + ks * 64 + lhi * 16);
      acc[pt] = __builtin_amdgcn_mfma_f32_16x16x32_bf16(wfrag[ks], xfrag, acc[pt], 0, 0, 0);
    }
  }
  __syncthreads();   // invn_s ready

  // ---- softmax over k (64 values per pixel column)
  float lg[4][4], linv[4];
#pragma unroll
  for (int pt = 0; pt < 4; ++pt) {
    linv[pt] = invn_s[pt * 16 + l15];
    float m = -1e30f;
#pragma unroll
    for (int r = 0; r < 4; ++r) { lg[pt][r] = acc[pt][r] * linv[pt]; m = fmaxf(m, lg[pt][r]); }
    m = fmaxf(m, __shfl_xor(m, 16));
    m = fmaxf(m, __shfl_xor(m, 32));
    if (lhi == 0) wredm[wave][pt][l15] = m;
  }
  __syncthreads();
#pragma unroll
  for (int pt = 0; pt < 4; ++pt) {
    float m = fmaxf(fmaxf(wredm[0][pt][l15], wredm[1][pt][l15]),
                    fmaxf(wredm[2][pt][l15], wredm[3][pt][l15]));
    float s = 0.f;
#pragma unroll
    for (int r = 0; r < 4; ++r) { lg[pt][r] = __expf(lg[pt][r] - m); s += lg[pt][r]; }
    s += __shfl_xor(s, 16);
    s += __shfl_xor(s, 32);
    if (lhi == 0) wreds[wave][pt][l15] = s;
  }
  __syncthreads();

  ushort* a2b = a2 + (size_t)n * K_DIM * P_PAD;
  float asr[4] = {0.f, 0.f, 0.f, 0.f};
#pragma unroll
  for (int pt = 0; pt < 4; ++pt) {
    float stot = wreds[0][pt][l15] + wreds[1][pt][l15] +
                 wreds[2][pt][l15] + wreds[3][pt][l15];
    float rs = 1.0f / stot;
    int p = p0 + pt * 16 + l15;
    bool vv = p < P_DIM;
#pragma unroll
    for (int r = 0; r < 4; ++r) {
      float a = lg[pt][r] * rs;
      if (vv) asr[r] += a;
      if (p < P_PAD) {
        int k = wave * 16 + lhi * 4 + r;
        a2b[(size_t)k * P_PAD + p] = vv ? f2bf(a * linv[pt]) : (ushort)0;
      }
    }
  }
  // asum over this block's pixels: reduce across l15 lanes
#pragma unroll
  for (int r = 0; r < 4; ++r) {
    float v = asr[r];
    v += __shfl_xor(v, 1); v += __shfl_xor(v, 2);
    v += __shfl_xor(v, 4); v += __shfl_xor(v, 8);
    if (l15 == 0) {
      int k = wave * 16 + lhi * 4 + r;
      asum_part[((size_t)n * K_DIM + k) * PTILES + bpt] = v;
    }
  }
}

// ---------------------------------------------------------------------------
// Kernel B: agg[n,k,c] = sum_p a2[k,p]*x[c,p] via MFMA (A=a2, B=x direct from
// global, fp32->bf16 in flight). Block = (c-tile of 64, n); wave w owns c-col
// subtile 16w. Fused epilogue: out = acc - asum*centroid. x read exactly once.
// ---------------------------------------------------------------------------
__global__ __launch_bounds__(256) void netvlad_agg(
    const float* __restrict__ x, const ushort* __restrict__ a2,
    const float* __restrict__ asum_part, const float* __restrict__ cent,
    float* __restrict__ out)
{
  const int n = blockIdx.y, ct = blockIdx.x, c0 = ct * 64;
  const int tid = threadIdx.x, wave = tid >> 6, lane = tid & 63;
  const int l15 = lane & 15, lhi = lane >> 4;

  __shared__ float asum_s[64];
  if (tid < 64) {
    const float* ap = asum_part + ((size_t)n * K_DIM + tid) * PTILES;
    float s = 0.f;
#pragma unroll
    for (int j = 0; j < PTILES; ++j) s += ap[j];
    asum_s[tid] = s;
  }
  __syncthreads();

  f32x4 acc[4];
#pragma unroll
  for (int mt = 0; mt < 4; ++mt) acc[mt] = (f32x4){0.f, 0.f, 0.f, 0.f};

  const float*  xrow = x + (size_t)n * C_DIM * P_DIM
                         + (size_t)(c0 + wave * 16 + l15) * P_DIM;
  const ushort* ab   = a2 + (size_t)n * K_DIM * P_PAD;

  for (int ks = 0; ks < 29; ++ks) {
    int pb = ks * 32 + lhi * 8;
    short8 bfrag;
    if (pb + 8 <= P_DIM) {
      float4 f0 = *(const float4*)(xrow + pb);
      float4 f1 = *(const float4*)(xrow + pb + 4);
      bfrag[0] = (short)f2bf(f0.x); bfrag[1] = (short)f2bf(f0.y);
      bfrag[2] = (short)f2bf(f0.z); bfrag[3] = (short)f2bf(f0.w);
      bfrag[4] = (short)f2bf(f1.x); bfrag[5] = (short)f2bf(f1.y);
      bfrag[6] = (short)f2bf(f1.z); bfrag[7] = (short)f2bf(f1.w);
    } else {
#pragma unroll
      for (int j = 0; j < 8; ++j)
        bfrag[j] = (pb + j < P_DIM) ? (short)f2bf(xrow[pb + j]) : (short)0;
    }
#pragma unroll
    for (int mt = 0; mt < 4; ++mt) {
      short8 afrag = *(const short8*)(ab + (size_t)(mt * 16 + l15) * P_PAD
                                         + ks * 32 + lhi * 8);
      acc[mt] = __builtin_amdgcn_mfma_f32_16x16x32_bf16(afrag, bfrag, acc[mt], 0, 0, 0);
    }
  }

  const int c = c0 + wave * 16 + l15;
#pragma unroll
  for (int mt = 0; mt < 4; ++mt) {
#pragma unroll
    for (int r = 0; r < 4; ++r) {
      int k = mt * 16 + lhi * 4 + r;
      out[((size_t)n * K_DIM + k) * C_DIM + c] =
          acc[mt][r] - asum_s[k] * cent[(size_t)k * C_DIM + c];
    }
  }
}

extern "C" void kernel_launch(void* const* d_in, const int* in_sizes, int n_in,
                              void* d_out, int out_size, void* d_ws, size_t ws_size,
                              hipStream_t stream) {
  const float* x    = (const float*)d_in[0];
  const float* w    = (const float*)d_in[1];
  const float* cent = (const float*)d_in[2];
  float* out = (float*)d_out;

  ushort* a2        = (ushort*)d_ws;
  float*  asum_part = (float*)((char*)d_ws + A2_ELEMS * sizeof(ushort));

  netvlad_assign<<<dim3(PTILES, N_DIM), 256, 0, stream>>>(x, w, a2, asum_part);
  netvlad_agg   <<<dim3(8, N_DIM),      256, 0, stream>>>(x, a2, asum_part, cent, out);
}